// Round 12
// baseline (4894.793 us; speedup 1.0000x reference)
//
#include <hip/hip_runtime.h>
#include <math.h>

#define RR 512
#define BB 16
#define TT 64
#define KC 2
#define NN 256
#define NBLK 256

__device__ __forceinline__ float sigmoidf_(float x) {
    return 1.0f / (1.0f + __expf(-x));
}
__device__ __forceinline__ float wave_sum(float v) {
    #pragma unroll
    for (int off = 32; off > 0; off >>= 1) v += __shfl_xor(v, off, 64);
    return v;
}
__device__ __forceinline__ float wave_max(float v) {
    #pragma unroll
    for (int off = 32; off > 0; off >>= 1) v = fmaxf(v, __shfl_xor(v, off, 64));
    return v;
}

// ---- relaxed agent-scope word ops (MALL-coherent, no cache fences) ----
__device__ __forceinline__ float ldA(const float* p) {
    return __hip_atomic_load(p, __ATOMIC_RELAXED, __HIP_MEMORY_SCOPE_AGENT);
}
__device__ __forceinline__ void stA(float* p, float v) {
    __hip_atomic_store(p, v, __ATOMIC_RELAXED, __HIP_MEMORY_SCOPE_AGENT);
}
__device__ __forceinline__ unsigned ldU(const unsigned* p) {
    return __hip_atomic_load(p, __ATOMIC_RELAXED, __HIP_MEMORY_SCOPE_AGENT);
}
__device__ __forceinline__ void stU(unsigned* p, unsigned v) {
    __hip_atomic_store(p, v, __ATOMIC_RELAXED, __HIP_MEMORY_SCOPE_AGENT);
}

struct f8 { float4 a, b; };
// split-slice mapping: lane's 8 floats of a 512-row = [lane*4,+4) and
// [256+lane*4,+4). Conflict-free LDS b128. Used for LDS-resident operands.
__device__ __forceinline__ f8 ld8s(const float* row, int lane) {
    f8 r;
    r.a = *(const float4*)(row + lane * 4);
    r.b = *(const float4*)(row + 256 + lane * 4);
    return r;
}
__device__ __forceinline__ void st8s(float* row, const f8& v, int lane) {
    *(float4*)(row + lane * 4) = v.a;
    *(float4*)(row + 256 + lane * 4) = v.b;
}
// stride-64 (transposed) mapping: lane's 8 floats = {lane + i*64, i=0..7}.
// Each component load is UNIT-STRIDE across lanes -> perfectly coalesced
// MALL word transactions. Used for MALL-resident operands (mbuf).
__device__ __forceinline__ f8 ld8t(const float* row, int lane) {
    f8 r;
    r.a.x = row[lane];        r.a.y = row[64 + lane];
    r.a.z = row[128 + lane];  r.a.w = row[192 + lane];
    r.b.x = row[256 + lane];  r.b.y = row[320 + lane];
    r.b.z = row[384 + lane];  r.b.w = row[448 + lane];
    return r;
}
__device__ __forceinline__ f8 ld8sA(const float* row, int lane) {
    f8 r;
    const float* p0 = row + lane * 4;
    const float* p1 = row + 256 + lane * 4;
    r.a.x = ldA(p0 + 0); r.a.y = ldA(p0 + 1); r.a.z = ldA(p0 + 2); r.a.w = ldA(p0 + 3);
    r.b.x = ldA(p1 + 0); r.b.y = ldA(p1 + 1); r.b.z = ldA(p1 + 2); r.b.w = ldA(p1 + 3);
    return r;
}
__device__ __forceinline__ float dot8(const f8& x, const f8& y) {
    return x.a.x*y.a.x + x.a.y*y.a.y + x.a.z*y.a.z + x.a.w*y.a.w
         + x.b.x*y.b.x + x.b.y*y.b.y + x.b.z*y.b.z + x.b.w*y.b.w;
}
// inline function, NOT a macro (macro param `w` collides with float4::w)
__device__ __forceinline__ void upd8(f8& m, const f8& u, float zf) {
    m.a.x = zf * (m.a.x + u.a.x); m.a.y = zf * (m.a.y + u.a.y);
    m.a.z = zf * (m.a.z + u.a.z); m.a.w = zf * (m.a.w + u.a.w);
    m.b.x = zf * (m.b.x + u.b.x); m.b.y = zf * (m.b.y + u.b.y);
    m.b.z = zf * (m.b.z + u.b.z); m.b.w = zf * (m.b.w + u.b.w);
}
__device__ __forceinline__ void fmaacc8(f8& acc, float sc, const f8& m, float wgt) {
    acc.a.x = acc.a.x*sc + wgt*m.a.x; acc.a.y = acc.a.y*sc + wgt*m.a.y;
    acc.a.z = acc.a.z*sc + wgt*m.a.z; acc.a.w = acc.a.w*sc + wgt*m.a.w;
    acc.b.x = acc.b.x*sc + wgt*m.b.x; acc.b.y = acc.b.y*sc + wgt*m.b.y;
    acc.b.z = acc.b.z*sc + wgt*m.b.z; acc.b.w = acc.b.w*sc + wgt*m.b.w;
}

// Payload-halving butterfly: p[0..15] per-b partials across 64 lanes ->
// each lane returns the full sum for b = (lane>>2)&15.
__device__ __forceinline__ float reduce16(float* p, int lane) {
    float q[8];
    {
        bool hi = (lane & 32) != 0;
        #pragma unroll
        for (int i = 0; i < 8; ++i) {
            float snd = hi ? p[i] : p[i + 8];
            float r = __shfl_xor(snd, 32, 64);
            q[i] = (hi ? p[i + 8] : p[i]) + r;
        }
    }
    float s4[4];
    {
        bool hi = (lane & 16) != 0;
        #pragma unroll
        for (int i = 0; i < 4; ++i) {
            float snd = hi ? q[i] : q[i + 4];
            float r = __shfl_xor(snd, 16, 64);
            s4[i] = (hi ? q[i + 4] : q[i]) + r;
        }
    }
    float d2[2];
    {
        bool hi = (lane & 8) != 0;
        #pragma unroll
        for (int i = 0; i < 2; ++i) {
            float snd = hi ? s4[i] : s4[i + 2];
            float r = __shfl_xor(snd, 8, 64);
            d2[i] = (hi ? s4[i + 2] : s4[i]) + r;
        }
    }
    float v;
    {
        bool hi = (lane & 4) != 0;
        float snd = hi ? d2[0] : d2[1];
        float r = __shfl_xor(snd, 4, 64);
        v = (hi ? d2[1] : d2[0]) + r;
    }
    v += __shfl_xor(v, 2, 64);
    v += __shfl_xor(v, 1, 64);
    return v;
}

__device__ __forceinline__ float gatedotR(const f8* A, const f8& w, int lane) {
    float p[16];
    #pragma unroll
    for (int b = 0; b < 16; ++b) p[b] = dot8(A[b], w);
    return reduce16(p, lane);
}
// gatedot streaming rows from LDS (low register pressure, block-local)
__device__ __forceinline__ float gatedotL(const float* act, const f8& w, int lane) {
    float p[16];
    #pragma unroll
    for (int b = 0; b < 16; ++b) {
        f8 r = ld8s(act + b * 512, lane);
        p[b] = dot8(r, w);
    }
    return reduce16(p, lane);
}
__device__ __forceinline__ void ldacts(f8* A, const float* act, int lane) {
    #pragma unroll
    for (int b = 0; b < 16; ++b) A[b] = ld8s(act + b * 512, lane);
}

// ---- store-slot barrier (RMW-free, fence-free). slots[256] hold each
// block's monotonically increasing generation. Arrival = per-wave vmcnt
// drain -> syncthreads -> one relaxed store. Wait = wave-0 lanes poll until
// __all(slot >= tgt). No release hop, no counter reset, no ABA (monotone).
__device__ __forceinline__ void barArrive(unsigned* slots, int sidx, unsigned tgt) {
    asm volatile("s_waitcnt vmcnt(0)" ::: "memory");
    __syncthreads();
    if (threadIdx.x == 0) stU(slots + sidx, tgt);
}
__device__ __forceinline__ void gridWait(unsigned* slots, unsigned tgt) {
    if (threadIdx.x < 64) {
        const unsigned* base = slots + threadIdx.x * 4;
        for (;;) {
            bool ok = (ldU(base + 0) >= tgt) & (ldU(base + 1) >= tgt)
                    & (ldU(base + 2) >= tgt) & (ldU(base + 3) >= tgt);
            if (__all(ok)) break;
            __builtin_amdgcn_s_sleep(1);
        }
    }
    __syncthreads();
}
__device__ __forceinline__ void groupWait(unsigned* slots, int gbase, unsigned tgt) {
    if (threadIdx.x < 64) {
        const unsigned* ps = slots + gbase + (threadIdx.x & 7);
        for (;;) {
            bool ok = ldU(ps) >= tgt;
            if (__all(ok)) break;
            __builtin_amdgcn_s_sleep(1);
        }
    }
    __syncthreads();
}

// ---------------------------------------------------------------------------
// k_pre: pre[t*16+b][j] = [emb|io] @ Wih_r^T + bih_r + bhh_r   (proven r1-r11)
// ---------------------------------------------------------------------------
__global__ void k_pre(const float* __restrict__ emb, const float* __restrict__ io,
                      const float* __restrict__ Wih, const float* __restrict__ bih,
                      const float* __restrict__ bhh, float* __restrict__ pre)
{
    __shared__ float As[16][65];
    __shared__ float Bs[16][65];
    int tid = threadIdx.x;
    int row0 = blockIdx.y * 64;
    int col0 = blockIdx.x * 64;
    int ty = tid >> 4, tx = tid & 15;
    float acc[4][4] = {};
    int lr = tid >> 2;
    int lk4 = (tid & 3) * 4;
    for (int k0 = 0; k0 < 1024; k0 += 16) {
        int grow = row0 + lr;
        int b = grow & 15;
        #pragma unroll
        for (int q = 0; q < 4; ++q) {
            int k = k0 + lk4 + q;
            float v = (k < RR) ? emb[(size_t)grow * RR + k]
                               : io[(size_t)b * RR + (k - RR)];
            As[lk4 + q][lr] = v;
        }
        #pragma unroll
        for (int q = 0; q < 4; ++q) {
            int k = k0 + lk4 + q;
            Bs[lk4 + q][lr] = Wih[(size_t)(col0 + lr) * 1024 + k];
        }
        __syncthreads();
        #pragma unroll
        for (int kk = 0; kk < 16; ++kk) {
            float a[4], bbv[4];
            #pragma unroll
            for (int i = 0; i < 4; ++i) a[i] = As[kk][ty * 4 + i];
            #pragma unroll
            for (int j = 0; j < 4; ++j) bbv[j] = Bs[kk][tx * 4 + j];
            #pragma unroll
            for (int i = 0; i < 4; ++i)
                #pragma unroll
                for (int j = 0; j < 4; ++j)
                    acc[i][j] += a[i] * bbv[j];
        }
        __syncthreads();
    }
    #pragma unroll
    for (int i = 0; i < 4; ++i) {
        int grow = row0 + ty * 4 + i;
        #pragma unroll
        for (int j = 0; j < 4; ++j) {
            int gcol = col0 + tx * 4 + j;
            pre[(size_t)grow * 2048 + gcol] = acc[i][j] + bih[gcol] + bhh[gcol];
        }
    }
}

struct P {
    const float *pre, *Whh_r, *Wc, *bc, *Wih_w, *Whh_w, *bih_w, *bhh_w;
    const float *hr0, *cr0, *hw0, *cw0, *M0;
    float *mbuf, *comppre, *mpart, *mxpart, *sumpart;
    float *hrb0, *hrb1, *crS, *hwb0, *hwb1, *cwS;
    float *outputs, *Mw;
    unsigned *slots;
};

// ---------------------------------------------------------------------------
// Persistent kernel: 64-step recurrence. M + staged activations in LDS;
// weights + cr/cw in registers; store-slot barriers; cross-block data via
// relaxed agent-scope word atomics with COALESCED (unit-stride) lane maps.
// ---------------------------------------------------------------------------
__global__ void __launch_bounds__(256, 1) k_persist(P p)
{
    const int tid = threadIdx.x;
    const int bid = blockIdx.x;
    const int wv = tid >> 6;
    const int lane = tid & 63;
    const int u0 = bid * 2;
    const int kb = (bid & 7) * 4 + (bid >> 6);   // (k,b) group
    const int w2 = (bid >> 3) & 7;               // slot within group
    const int bM = kb & 15;
    const int rowG = kb * 256 + w2 * 32;
    const int sidx = kb * 8 + w2;                // barrier slot (group-contig)
    const int gbase = kb * 8;

    __shared__ float Mlds[32][512];       // 64 KB
    __shared__ float actH[16 * 512];      // 32 KB: hr_t; comppre/E overlay in D
    __shared__ float actW[16 * 512];      // 32 KB: hw_{t-1} staged
    __shared__ float smacc[4][512];       // 8 KB
    __shared__ float smx4[4], ssh4[4];
    __shared__ float simL[32];
    __shared__ float gsm[2][4][16];
    __shared__ float cc[2][2][16];
    __shared__ float wmx[16][2], wsm[16][2];
    __shared__ float bcsh[2];

    unsigned tg = 0;
    float mxK = 0.f, sumInvK = 0.f;
    float crR = 0.f, cwR = 0.f;

    // ---- register-resident weight slices.
    // split-slice mapping for weights dotted against LDS-resident operands;
    // stride-64 (ld8t) mapping for weights dotted against MALL-resident mbuf.
    const int jA = wv * 512 + u0;
    const f8 wR0 = ld8s(p.Whh_r + (size_t)jA * 512, lane);
    const f8 wR1 = ld8s(p.Whh_r + (size_t)(jA + 1) * 512, lane);
    const f8 wW0 = ld8s(p.Whh_w + (size_t)jA * 512, lane);
    const f8 wW1 = ld8s(p.Whh_w + (size_t)(jA + 1) * 512, lane);
    const f8 wI0 = ld8s(p.Wih_w + (size_t)jA * 512, lane);
    const f8 wI1 = ld8s(p.Wih_w + (size_t)(jA + 1) * 512, lane);
    const float bw0 = p.bih_w[jA] + p.bhh_w[jA];
    const float bw1 = p.bih_w[jA + 1] + p.bhh_w[jA + 1];
    const int jj = wv >> 1, part = wv & 1;
    const int jC = u0 + jj;
    f8 wC0, wC1 = {};
    if (part == 0) {
        wC0 = ld8s(p.Wc + (size_t)jC * 1536, lane);          // vs hr (LDS)
        wC1 = ld8t(p.Wc + (size_t)jC * 1536 + 512, lane);    // vs m0 (MALL)
    } else {
        wC0 = ld8t(p.Wc + (size_t)jC * 1536 + 1024, lane);   // vs m1 (MALL)
    }
    if (tid < 2) bcsh[tid] = p.bc[u0 + tid];
    if (tid < 32) cwR = p.cw0[(tid & 15) * 512 + u0 + (tid >> 4)];

    // ---- load this block's M rows: global M0 -> LDS (once)
    {
        const float4* src = (const float4*)(p.M0 + (size_t)rowG * 512);
        float4* dst = (float4*)&Mlds[0][0];
        #pragma unroll 4
        for (int idx = tid; idx < 32 * 128; idx += 256)
            dst[idx] = src[idx];
    }

    // ---- prologue: read-LSTM step 0 -> hr_0 (hrb0), cr_0 (register)
    {
        f8 A[16]; ldacts(A, p.hr0, lane);
        float gv0 = gatedotR(A, wR0, lane);
        float gv1 = gatedotR(A, wR1, lane);
        if ((lane & 3) == 0) {
            int b = (lane >> 2) & 15;
            gsm[0][wv][b] = gv0 + p.pre[(size_t)b * 2048 + jA];
            gsm[1][wv][b] = gv1 + p.pre[(size_t)b * 2048 + jA + 1];
        }
        __syncthreads();
        if (tid < 32) {
            int b = tid & 15, uu = tid >> 4;
            int u = u0 + uu;
            float gi = sigmoidf_(gsm[uu][0][b]);
            float gf = sigmoidf_(gsm[uu][1][b]);
            float gg = tanhf(gsm[uu][2][b]);
            float go = sigmoidf_(gsm[uu][3][b]);
            float c = gf * p.cr0[b * 512 + u] + gi * gg;
            crR = c;
            stA(p.hrb0 + b * 512 + u, go * tanhf(c));
        }
        ++tg; barArrive(p.slots, sidx, tg); gridWait(p.slots, tg);
    }

    for (int t = 0; t < TT; ++t) {
        const float* hrcur  = (t & 1) ? p.hrb1 : p.hrb0;
        float*       hrnext = (t & 1) ? p.hrb0 : p.hrb1;
        const float* hwprev = (t == 0) ? p.hw0 : (((t - 1) & 1) ? p.hwb1 : p.hwb0);
        float*       hwnext = (t & 1) ? p.hwb1 : p.hwb0;

        // ---- stage hr_t and hw_{t-1} into LDS: coalesced unit-stride word
        // atomic loads (identity LDS layout; LDS word writes conflict-free)
        {
            #pragma unroll
            for (int q = 0; q < 8; ++q) {
                int base = q * 1024;
                float h0 = ldA(hrcur + base + tid);
                float h1 = ldA(hrcur + base + 256 + tid);
                float h2 = ldA(hrcur + base + 512 + tid);
                float h3 = ldA(hrcur + base + 768 + tid);
                float g0 = ldA(hwprev + base + tid);
                float g1 = ldA(hwprev + base + 256 + tid);
                float g2 = ldA(hwprev + base + 512 + tid);
                float g3 = ldA(hwprev + base + 768 + tid);
                actH[base + tid] = h0;       actH[base + 256 + tid] = h1;
                actH[base + 512 + tid] = h2; actH[base + 768 + tid] = h3;
                actW[base + tid] = g0;       actW[base + 256 + tid] = g1;
                actW[base + 512 + tid] = g2; actW[base + 768 + tid] = g3;
            }
        }
        __syncthreads();

        // ========= stage A: deferred M update (local z) + sim + online partials
        {
            f8 h = ld8s(actH + bM * 512, lane);
            f8 w8 = {};
            if (t > 0) w8 = ld8s(actW + bM * 512, lane);
            float mx = -3.0e38f, ssum = 0.f;
            f8 macc = {};
            #pragma unroll
            for (int ii = 0; ii < 8; ++ii) {
                int rl = wv * 8 + ii;
                float4* mp0 = (float4*)&Mlds[rl][lane * 4];
                float4* mp1 = (float4*)&Mlds[rl][256 + lane * 4];
                f8 m; m.a = *mp0; m.b = *mp1;
                if (t > 0) {
                    float zf = 1.0f - __expf(simL[rl] - mxK) * sumInvK;
                    upd8(m, w8, zf);
                    *mp0 = m.a; *mp1 = m.b;
                }
                float s = wave_sum(dot8(m, h));
                float nmx = fmaxf(mx, s);
                float sc = __expf(mx - nmx);
                float wgt = __expf(s - nmx);
                fmaacc8(macc, sc, m, wgt);
                ssum = ssum * sc + wgt;
                mx = nmx;
                if (lane == 0) simL[rl] = s;
            }
            if (lane == 0) { smx4[wv] = mx; ssh4[wv] = ssum; }
            __syncthreads();
            float MXb = fmaxf(fmaxf(smx4[0], smx4[1]), fmaxf(smx4[2], smx4[3]));
            float sc2 = __expf(mx - MXb);
            float* d0 = &smacc[wv][lane * 4];
            float* d1 = &smacc[wv][256 + lane * 4];
            d0[0] = macc.a.x * sc2; d0[1] = macc.a.y * sc2;
            d0[2] = macc.a.z * sc2; d0[3] = macc.a.w * sc2;
            d1[0] = macc.b.x * sc2; d1[1] = macc.b.y * sc2;
            d1[2] = macc.b.z * sc2; d1[3] = macc.b.w * sc2;
            __syncthreads();
            for (int r = tid; r < 512; r += 256)
                stA(&p.mpart[(size_t)(kb * 8 + w2) * 512 + r],
                    smacc[0][r] + smacc[1][r] + smacc[2][r] + smacc[3][r]);
            if (tid == 0) {
                float sB = ssh4[0] * __expf(smx4[0] - MXb)
                         + ssh4[1] * __expf(smx4[1] - MXb)
                         + ssh4[2] * __expf(smx4[2] - MXb)
                         + ssh4[3] * __expf(smx4[3] - MXb);
                stA(&p.mxpart[kb * 8 + w2], MXb);
                stA(&p.sumpart[kb * 8 + w2], sB);
            }
        }
        // ========= stage A2: read-LSTM gates for t+1 (LDS activations)
        if (t < 63) {
            float gv0 = gatedotL(actH, wR0, lane);
            float gv1 = gatedotL(actH, wR1, lane);
            if ((lane & 3) == 0) {
                int b = (lane >> 2) & 15;
                gsm[0][wv][b] = gv0 + p.pre[(size_t)((t + 1) * 16 + b) * 2048 + jA];
                gsm[1][wv][b] = gv1 + p.pre[(size_t)((t + 1) * 16 + b) * 2048 + jA + 1];
            }
            __syncthreads();
            if (tid < 32) {
                int b = tid & 15, uu = tid >> 4;
                int u = u0 + uu;
                float gi = sigmoidf_(gsm[uu][0][b]);
                float gf = sigmoidf_(gsm[uu][1][b]);
                float gg = tanhf(gsm[uu][2][b]);
                float go = sigmoidf_(gsm[uu][3][b]);
                float c = gf * crR + gi * gg;
                crR = c;
                stA(hrnext + b * 512 + u, go * tanhf(c));
            }
        }

        // ========= stage B-lite: group (k,b) softmax stats + mbuf slice
        ++tg; barArrive(p.slots, sidx, tg); groupWait(p.slots, gbase, tg);
        {
            float mxp[8];
            #pragma unroll
            for (int w3 = 0; w3 < 8; ++w3) mxp[w3] = ldA(&p.mxpart[kb * 8 + w3]);
            float MX = -3.0e38f;
            #pragma unroll
            for (int w3 = 0; w3 < 8; ++w3) MX = fmaxf(MX, mxp[w3]);
            float SUM = 0.f;
            #pragma unroll
            for (int w3 = 0; w3 < 8; ++w3)
                SUM += ldA(&p.sumpart[kb * 8 + w3]) * __expf(mxp[w3] - MX);
            mxK = MX;
            sumInvK = 1.0f / SUM;
            if (tid < 64) {
                int r = w2 * 64 + tid;
                float acc = 0.f;
                #pragma unroll
                for (int w3 = 0; w3 < 8; ++w3)
                    acc += __expf(mxp[w3] - MX)
                         * ldA(&p.mpart[(size_t)(kb * 8 + w3) * 512 + r]);
                stA(&p.mbuf[(size_t)kb * 512 + r], acc * sumInvK);
            }
        }
        ++tg; barArrive(p.slots, sidx, tg); gridWait(p.slots, tg);

        // ========= stage C: comppre GEMV + hoisted vh = hw_prev . Whh_w
        float vh0, vh1;
        {
            vh0 = gatedotL(actW, wW0, lane);
            vh1 = gatedotL(actW, wW1, lane);
        }
        {
            float v;
            f8 Am[16];
            const float* msrc = p.mbuf + (part ? 16 * 512 : 0);
            #pragma unroll
            for (int b = 0; b < 16; ++b) {
                const float* rowp = msrc + b * 512 + lane;   // stride-64 map
                Am[b].a.x = ldA(rowp + 0);
                Am[b].a.y = ldA(rowp + 64);
                Am[b].a.z = ldA(rowp + 128);
                Am[b].a.w = ldA(rowp + 192);
                Am[b].b.x = ldA(rowp + 256);
                Am[b].b.y = ldA(rowp + 320);
                Am[b].b.z = ldA(rowp + 384);
                Am[b].b.w = ldA(rowp + 448);
            }
            if (part == 0) {
                v = gatedotL(actH, wC0, lane) + gatedotR(Am, wC1, lane);
            } else {
                v = gatedotR(Am, wC0, lane);
            }
            if ((lane & 3) == 0) {
                int b = (lane >> 2) & 15;
                cc[jj][part][b] = v;
            }
            __syncthreads();
            if (tid < 32) {
                int b = tid & 15, jj2 = tid >> 4;
                stA(&p.comppre[b * 512 + (u0 + jj2)],
                    cc[jj2][0][b] + cc[jj2][1][b] + bcsh[jj2]);
            }
        }
        ++tg; barArrive(p.slots, sidx, tg); gridWait(p.slots, tg);

        // ========= stage D: stage comppre -> actH overlay (coalesced; hr dead
        // after C), cooperative softmax -> E in same overlay, write-LSTM gates
        {
            #pragma unroll
            for (int i = 0; i < 32; ++i)
                actH[i * 256 + tid] = ldA(p.comppre + i * 256 + tid);
            __syncthreads();
            float v[8][4];
            #pragma unroll
            for (int k = 0; k < 8; ++k) {
                int idx = k * 1024 + tid * 4;
                #pragma unroll
                for (int j = 0; j < 4; ++j) v[k][j] = actH[idx + j];
            }
            const int bpar = wv >> 1;     // tid>>7
            #pragma unroll
            for (int k = 0; k < 8; ++k) {
                float mk = fmaxf(fmaxf(v[k][0], v[k][1]), fmaxf(v[k][2], v[k][3]));
                mk = wave_max(mk);
                if (lane == 0) wmx[2 * k + bpar][wv & 1] = mk;
            }
            __syncthreads();                 // all v reads done before E write
            float4* Eld4 = (float4*)actH;
            #pragma unroll
            for (int k = 0; k < 8; ++k) {
                float mxb = fmaxf(wmx[2 * k + bpar][0], wmx[2 * k + bpar][1]);
                float e0 = __expf(v[k][0] - mxb), e1 = __expf(v[k][1] - mxb);
                float e2 = __expf(v[k][2] - mxb), e3 = __expf(v[k][3] - mxb);
                Eld4[k * 256 + tid] = make_float4(e0, e1, e2, e3);
                float sv = wave_sum(e0 + e1 + e2 + e3);
                if (lane == 0) wsm[2 * k + bpar][wv & 1] = sv;
            }
            __syncthreads();
            float ti0 = gatedotL(actH, wI0, lane);
            float ti1 = gatedotL(actH, wI1, lane);
            if ((lane & 3) == 0) {
                int bb = (lane >> 2) & 15;
                float siv = 1.0f / (wsm[bb][0] + wsm[bb][1]);
                gsm[0][wv][bb] = ti0 * siv + vh0 + bw0;
                gsm[1][wv][bb] = ti1 * siv + vh1 + bw1;
            }
            __syncthreads();
            if (tid < 32) {
                int bb = tid & 15, uu = tid >> 4;
                int u = u0 + uu;
                float gi = sigmoidf_(gsm[uu][0][bb]);
                float gf = sigmoidf_(gsm[uu][1][bb]);
                float gg = tanhf(gsm[uu][2][bb]);
                float go = sigmoidf_(gsm[uu][3][bb]);
                float c = gf * cwR + gi * gg;
                cwR = c;
                float h = go * tanhf(c);
                stA(hwnext + bb * 512 + u, h);
                p.outputs[(size_t)t * 8192 + bb * 512 + u] = h;
            }
        }
        ++tg; barArrive(p.slots, sidx, tg); gridWait(p.slots, tg);
    }

    // ---- epilogue: final deferred M update with (z_63, hw_63 = hwb1);
    //      write LDS M -> Mf; flush cr/cw registers to d_out
    {
        f8 w8 = ld8sA(p.hwb1 + (size_t)bM * 512, lane);
        #pragma unroll
        for (int ii = 0; ii < 8; ++ii) {
            int rl = wv * 8 + ii;
            float zf = 1.0f - __expf(simL[rl] - mxK) * sumInvK;
            f8 m;
            m.a = *(float4*)&Mlds[rl][lane * 4];
            m.b = *(float4*)&Mlds[rl][256 + lane * 4];
            upd8(m, w8, zf);
            st8s(p.Mw + (size_t)(rowG + rl) * 512, m, lane);
        }
        if (tid < 32) {
            int b = tid & 15, uu = tid >> 4;
            int u = u0 + uu;
            p.crS[b * 512 + u] = crR;
            p.cwS[b * 512 + u] = cwR;
        }
    }
}

extern "C" void kernel_launch(void* const* d_in, const int* in_sizes, int n_in,
                              void* d_out, int out_size, void* d_ws, size_t ws_size,
                              hipStream_t stream) {
    const float* emb   = (const float*)d_in[0];
    const float* hr0   = (const float*)d_in[1];
    const float* cr0   = (const float*)d_in[2];
    const float* hw0   = (const float*)d_in[3];
    const float* cw0   = (const float*)d_in[4];
    const float* io    = (const float*)d_in[5];
    const float* M0    = (const float*)d_in[6];
    const float* Wih_r = (const float*)d_in[7];
    const float* bih_r = (const float*)d_in[9];
    const float* bhh_r = (const float*)d_in[10];

    float* out = (float*)d_out;
    float* outputs = out;                    // [64][16][512]
    float* hrS1 = out + 524288;              // hr slot = hr parity-1 buf
    float* crS  = out + 532480;
    float* hwS1 = out + 540672;              // hw slot = hw parity-1 buf
    float* cwS  = out + 548864;
    float* Mw   = out + 557056;              // Mf (written once at epilogue)

    float* ws = (float*)d_ws;
    float* pre     = ws;                     // 1024*2048
    float* mbuf    = ws + 2097152;           // 32*512
    float* comppre = mbuf + 16384;           // 16*512
    float* hrB0    = comppre + 8192;         // hr parity 0
    float* hwB0    = hrB0 + 8192;            // hw parity 0
    float* mpart   = hwB0 + 8192;            // 256*512
    float* mxpart  = mpart + 131072;         // 256
    float* sumpart = mxpart + 256;           // 256
    unsigned* slots = (unsigned*)(sumpart + 256); // 256 uints

    (void)hipMemsetAsync(slots, 0, 256 * sizeof(unsigned), stream);

    k_pre<<<dim3(32, 16), 256, 0, stream>>>(emb, io, Wih_r, bih_r, bhh_r, pre);

    P p;
    p.pre = pre;
    p.Whh_r = (const float*)d_in[8];
    p.Wc    = (const float*)d_in[11];
    p.bc    = (const float*)d_in[12];
    p.Wih_w = (const float*)d_in[13];
    p.Whh_w = (const float*)d_in[14];
    p.bih_w = (const float*)d_in[15];
    p.bhh_w = (const float*)d_in[16];
    p.hr0 = hr0; p.cr0 = cr0; p.hw0 = hw0; p.cw0 = cw0; p.M0 = M0;
    p.mbuf = mbuf; p.comppre = comppre;
    p.mpart = mpart; p.mxpart = mxpart; p.sumpart = sumpart;
    p.hrb0 = hrB0; p.hrb1 = hrS1; p.crS = crS;
    p.hwb0 = hwB0; p.hwb1 = hwS1; p.cwS = cwS;
    p.outputs = outputs; p.Mw = Mw;
    p.slots = slots;

    k_persist<<<NBLK, 256, 0, stream>>>(p);
}

// Round 13
// 2302.993 us; speedup vs baseline: 2.1254x; 2.1254x over previous
//
#include <hip/hip_runtime.h>
#include <math.h>

#define RR 512
#define BB 16
#define TT 64
#define KC 2
#define NN 256
#define NBLK 256

__device__ __forceinline__ float sigmoidf_(float x) {
    return 1.0f / (1.0f + __expf(-x));
}
__device__ __forceinline__ float wave_sum(float v) {
    #pragma unroll
    for (int off = 32; off > 0; off >>= 1) v += __shfl_xor(v, off, 64);
    return v;
}
__device__ __forceinline__ float wave_max(float v) {
    #pragma unroll
    for (int off = 32; off > 0; off >>= 1) v = fmaxf(v, __shfl_xor(v, off, 64));
    return v;
}

// ---- relaxed agent-scope atomic ops (MALL-coherent, no cache fences) ----
__device__ __forceinline__ float ldA(const float* p) {
    return __hip_atomic_load(p, __ATOMIC_RELAXED, __HIP_MEMORY_SCOPE_AGENT);
}
__device__ __forceinline__ void stA(float* p, float v) {
    __hip_atomic_store(p, v, __ATOMIC_RELAXED, __HIP_MEMORY_SCOPE_AGENT);
}
__device__ __forceinline__ unsigned ldU(const unsigned* p) {
    return __hip_atomic_load(p, __ATOMIC_RELAXED, __HIP_MEMORY_SCOPE_AGENT);
}
__device__ __forceinline__ void stU(unsigned* p, unsigned v) {
    __hip_atomic_store(p, v, __ATOMIC_RELAXED, __HIP_MEMORY_SCOPE_AGENT);
}
// 8-byte (2-float) relaxed atomics: 2x fewer MALL transactions, same
// per-thread-contiguous addressing as r11 (which was MALL-absorbed).
__device__ __forceinline__ float2 ldA2(const float* p) {
    unsigned long long v = __hip_atomic_load((const unsigned long long*)p,
                                             __ATOMIC_RELAXED, __HIP_MEMORY_SCOPE_AGENT);
    float2 r;
    r.x = __uint_as_float((unsigned)v);
    r.y = __uint_as_float((unsigned)(v >> 32));
    return r;
}
__device__ __forceinline__ void stA2(float* p, float x, float y) {
    unsigned long long v = ((unsigned long long)__float_as_uint(y) << 32)
                         | (unsigned long long)__float_as_uint(x);
    __hip_atomic_store((unsigned long long*)p, v, __ATOMIC_RELAXED,
                       __HIP_MEMORY_SCOPE_AGENT);
}

struct f8 { float4 a, b; };
// split-slice mapping: lane's 8 floats of a 512-row = [lane*4,+4) and
// [256+lane*4,+4). Conflict-free LDS b128. Used for LDS-resident operands.
__device__ __forceinline__ f8 ld8s(const float* row, int lane) {
    f8 r;
    r.a = *(const float4*)(row + lane * 4);
    r.b = *(const float4*)(row + 256 + lane * 4);
    return r;
}
__device__ __forceinline__ void st8s(float* row, const f8& v, int lane) {
    *(float4*)(row + lane * 4) = v.a;
    *(float4*)(row + 256 + lane * 4) = v.b;
}
// same addresses as r11's ld8sA, but 8B-atomic granularity
__device__ __forceinline__ f8 ld8sA2(const float* row, int lane) {
    float2 t0 = ldA2(row + lane * 4);
    float2 t1 = ldA2(row + lane * 4 + 2);
    float2 t2 = ldA2(row + 256 + lane * 4);
    float2 t3 = ldA2(row + 256 + lane * 4 + 2);
    f8 r;
    r.a = make_float4(t0.x, t0.y, t1.x, t1.y);
    r.b = make_float4(t2.x, t2.y, t3.x, t3.y);
    return r;
}
__device__ __forceinline__ float dot8(const f8& x, const f8& y) {
    return x.a.x*y.a.x + x.a.y*y.a.y + x.a.z*y.a.z + x.a.w*y.a.w
         + x.b.x*y.b.x + x.b.y*y.b.y + x.b.z*y.b.z + x.b.w*y.b.w;
}
// inline function, NOT a macro (macro param `w` collides with float4::w)
__device__ __forceinline__ void upd8(f8& m, const f8& u, float zf) {
    m.a.x = zf * (m.a.x + u.a.x); m.a.y = zf * (m.a.y + u.a.y);
    m.a.z = zf * (m.a.z + u.a.z); m.a.w = zf * (m.a.w + u.a.w);
    m.b.x = zf * (m.b.x + u.b.x); m.b.y = zf * (m.b.y + u.b.y);
    m.b.z = zf * (m.b.z + u.b.z); m.b.w = zf * (m.b.w + u.b.w);
}
__device__ __forceinline__ void fmaacc8(f8& acc, float sc, const f8& m, float wgt) {
    acc.a.x = acc.a.x*sc + wgt*m.a.x; acc.a.y = acc.a.y*sc + wgt*m.a.y;
    acc.a.z = acc.a.z*sc + wgt*m.a.z; acc.a.w = acc.a.w*sc + wgt*m.a.w;
    acc.b.x = acc.b.x*sc + wgt*m.b.x; acc.b.y = acc.b.y*sc + wgt*m.b.y;
    acc.b.z = acc.b.z*sc + wgt*m.b.z; acc.b.w = acc.b.w*sc + wgt*m.b.w;
}

// Payload-halving butterfly: p[0..15] per-b partials across 64 lanes ->
// each lane returns the full sum for b = (lane>>2)&15.
__device__ __forceinline__ float reduce16(float* p, int lane) {
    float q[8];
    {
        bool hi = (lane & 32) != 0;
        #pragma unroll
        for (int i = 0; i < 8; ++i) {
            float snd = hi ? p[i] : p[i + 8];
            float r = __shfl_xor(snd, 32, 64);
            q[i] = (hi ? p[i + 8] : p[i]) + r;
        }
    }
    float s4[4];
    {
        bool hi = (lane & 16) != 0;
        #pragma unroll
        for (int i = 0; i < 4; ++i) {
            float snd = hi ? q[i] : q[i + 4];
            float r = __shfl_xor(snd, 16, 64);
            s4[i] = (hi ? q[i + 4] : q[i]) + r;
        }
    }
    float d2[2];
    {
        bool hi = (lane & 8) != 0;
        #pragma unroll
        for (int i = 0; i < 2; ++i) {
            float snd = hi ? s4[i] : s4[i + 2];
            float r = __shfl_xor(snd, 8, 64);
            d2[i] = (hi ? s4[i + 2] : s4[i]) + r;
        }
    }
    float v;
    {
        bool hi = (lane & 4) != 0;
        float snd = hi ? d2[0] : d2[1];
        float r = __shfl_xor(snd, 4, 64);
        v = (hi ? d2[1] : d2[0]) + r;
    }
    v += __shfl_xor(v, 2, 64);
    v += __shfl_xor(v, 1, 64);
    return v;
}

__device__ __forceinline__ float gatedotR(const f8* A, const f8& w, int lane) {
    float p[16];
    #pragma unroll
    for (int b = 0; b < 16; ++b) p[b] = dot8(A[b], w);
    return reduce16(p, lane);
}
// gatedot streaming rows from LDS (low register pressure, block-local)
__device__ __forceinline__ float gatedotL(const float* act, const f8& w, int lane) {
    float p[16];
    #pragma unroll
    for (int b = 0; b < 16; ++b) {
        f8 r = ld8s(act + b * 512, lane);
        p[b] = dot8(r, w);
    }
    return reduce16(p, lane);
}
__device__ __forceinline__ void ldacts(f8* A, const float* act, int lane) {
    #pragma unroll
    for (int b = 0; b < 16; ++b) A[b] = ld8s(act + b * 512, lane);
}
__device__ __forceinline__ void ldactsA2(f8* A, const float* act, int lane) {
    #pragma unroll
    for (int b = 0; b < 16; ++b) A[b] = ld8sA2(act + b * 512, lane);
}

// ---- store-slot barrier (RMW-free, fence-free). slots[256] hold each
// block's monotonically increasing generation. Arrival = per-wave vmcnt
// drain -> syncthreads -> one relaxed store. Wait = wave-0 lanes poll until
// __all(slot >= tgt). No release hop, no counter reset, no ABA (monotone).
__device__ __forceinline__ void barArrive(unsigned* slots, int sidx, unsigned tgt) {
    asm volatile("s_waitcnt vmcnt(0)" ::: "memory");
    __syncthreads();
    if (threadIdx.x == 0) stU(slots + sidx, tgt);
}
__device__ __forceinline__ void gridWait(unsigned* slots, unsigned tgt) {
    if (threadIdx.x < 64) {
        const unsigned* base = slots + threadIdx.x * 4;
        for (;;) {
            bool ok = (ldU(base + 0) >= tgt) & (ldU(base + 1) >= tgt)
                    & (ldU(base + 2) >= tgt) & (ldU(base + 3) >= tgt);
            if (__all(ok)) break;
            __builtin_amdgcn_s_sleep(1);
        }
    }
    __syncthreads();
}
__device__ __forceinline__ void groupWait(unsigned* slots, int gbase, unsigned tgt) {
    if (threadIdx.x < 64) {
        const unsigned* ps = slots + gbase + (threadIdx.x & 7);
        for (;;) {
            bool ok = ldU(ps) >= tgt;
            if (__all(ok)) break;
            __builtin_amdgcn_s_sleep(1);
        }
    }
    __syncthreads();
}

// ---------------------------------------------------------------------------
// k_pre: pre[t*16+b][j] = [emb|io] @ Wih_r^T + bih_r + bhh_r   (proven r1-r11)
// ---------------------------------------------------------------------------
__global__ void k_pre(const float* __restrict__ emb, const float* __restrict__ io,
                      const float* __restrict__ Wih, const float* __restrict__ bih,
                      const float* __restrict__ bhh, float* __restrict__ pre)
{
    __shared__ float As[16][65];
    __shared__ float Bs[16][65];
    int tid = threadIdx.x;
    int row0 = blockIdx.y * 64;
    int col0 = blockIdx.x * 64;
    int ty = tid >> 4, tx = tid & 15;
    float acc[4][4] = {};
    int lr = tid >> 2;
    int lk4 = (tid & 3) * 4;
    for (int k0 = 0; k0 < 1024; k0 += 16) {
        int grow = row0 + lr;
        int b = grow & 15;
        #pragma unroll
        for (int q = 0; q < 4; ++q) {
            int k = k0 + lk4 + q;
            float v = (k < RR) ? emb[(size_t)grow * RR + k]
                               : io[(size_t)b * RR + (k - RR)];
            As[lk4 + q][lr] = v;
        }
        #pragma unroll
        for (int q = 0; q < 4; ++q) {
            int k = k0 + lk4 + q;
            Bs[lk4 + q][lr] = Wih[(size_t)(col0 + lr) * 1024 + k];
        }
        __syncthreads();
        #pragma unroll
        for (int kk = 0; kk < 16; ++kk) {
            float a[4], bbv[4];
            #pragma unroll
            for (int i = 0; i < 4; ++i) a[i] = As[kk][ty * 4 + i];
            #pragma unroll
            for (int j = 0; j < 4; ++j) bbv[j] = Bs[kk][tx * 4 + j];
            #pragma unroll
            for (int i = 0; i < 4; ++i)
                #pragma unroll
                for (int j = 0; j < 4; ++j)
                    acc[i][j] += a[i] * bbv[j];
        }
        __syncthreads();
    }
    #pragma unroll
    for (int i = 0; i < 4; ++i) {
        int grow = row0 + ty * 4 + i;
        #pragma unroll
        for (int j = 0; j < 4; ++j) {
            int gcol = col0 + tx * 4 + j;
            pre[(size_t)grow * 2048 + gcol] = acc[i][j] + bih[gcol] + bhh[gcol];
        }
    }
}

struct P {
    const float *pre, *Whh_r, *Wc, *bc, *Wih_w, *Whh_w, *bih_w, *bhh_w;
    const float *hr0, *cr0, *hw0, *cw0, *M0;
    float *mbuf, *comppre, *mpart, *mxpart, *sumpart;
    float *hrb0, *hrb1, *crS, *hwb0, *hwb1, *cwS;
    float *outputs, *Mw;
    unsigned *slots;
};

// ---------------------------------------------------------------------------
// Persistent kernel: 64-step recurrence. M + staged activations in LDS;
// weights + cr/cw in registers; store-slot barriers; cross-block data via
// relaxed agent-scope atomics at 8-byte granularity (r11 addressing).
// ---------------------------------------------------------------------------
__global__ void __launch_bounds__(256, 1) k_persist(P p)
{
    const int tid = threadIdx.x;
    const int bid = blockIdx.x;
    const int wv = tid >> 6;
    const int lane = tid & 63;
    const int u0 = bid * 2;
    const int kb = (bid & 7) * 4 + (bid >> 6);   // (k,b) group
    const int w2 = (bid >> 3) & 7;               // slot within group
    const int bM = kb & 15;
    const int rowG = kb * 256 + w2 * 32;
    const int sidx = kb * 8 + w2;                // barrier slot (group-contig)
    const int gbase = kb * 8;

    __shared__ float Mlds[32][512];       // 64 KB
    __shared__ float actH[16 * 512];      // 32 KB: hr_t staged; E overlay in D
    __shared__ float actW[16 * 512];      // 32 KB: hw_{t-1} staged
    __shared__ float smacc[4][512];       // 8 KB
    __shared__ float smx4[4], ssh4[4];
    __shared__ float simL[32];
    __shared__ float gsm[2][4][16];
    __shared__ float cc[2][2][16];
    __shared__ float wmx[16][2], wsm[16][2];
    __shared__ float bcsh[2];

    unsigned tg = 0;
    float mxK = 0.f, sumInvK = 0.f;
    float crR = 0.f, cwR = 0.f;

    // ---- register-resident weight slices (split-slice mapping)
    const int jA = wv * 512 + u0;
    const f8 wR0 = ld8s(p.Whh_r + (size_t)jA * 512, lane);
    const f8 wR1 = ld8s(p.Whh_r + (size_t)(jA + 1) * 512, lane);
    const f8 wW0 = ld8s(p.Whh_w + (size_t)jA * 512, lane);
    const f8 wW1 = ld8s(p.Whh_w + (size_t)(jA + 1) * 512, lane);
    const f8 wI0 = ld8s(p.Wih_w + (size_t)jA * 512, lane);
    const f8 wI1 = ld8s(p.Wih_w + (size_t)(jA + 1) * 512, lane);
    const float bw0 = p.bih_w[jA] + p.bhh_w[jA];
    const float bw1 = p.bih_w[jA + 1] + p.bhh_w[jA + 1];
    const int jj = wv >> 1, part = wv & 1;
    const int jC = u0 + jj;
    f8 wC0, wC1 = {};
    if (part == 0) {
        wC0 = ld8s(p.Wc + (size_t)jC * 1536, lane);
        wC1 = ld8s(p.Wc + (size_t)jC * 1536 + 512, lane);
    } else {
        wC0 = ld8s(p.Wc + (size_t)jC * 1536 + 1024, lane);
    }
    if (tid < 2) bcsh[tid] = p.bc[u0 + tid];
    if (tid < 32) cwR = p.cw0[(tid & 15) * 512 + u0 + (tid >> 4)];

    // ---- load this block's M rows: global M0 -> LDS (once)
    {
        const float4* src = (const float4*)(p.M0 + (size_t)rowG * 512);
        float4* dst = (float4*)&Mlds[0][0];
        #pragma unroll 4
        for (int idx = tid; idx < 32 * 128; idx += 256)
            dst[idx] = src[idx];
    }

    // ---- prologue: read-LSTM step 0 -> hr_0 (hrb0), cr_0 (register)
    {
        f8 A[16]; ldacts(A, p.hr0, lane);
        float gv0 = gatedotR(A, wR0, lane);
        float gv1 = gatedotR(A, wR1, lane);
        if ((lane & 3) == 0) {
            int b = (lane >> 2) & 15;
            gsm[0][wv][b] = gv0 + p.pre[(size_t)b * 2048 + jA];
            gsm[1][wv][b] = gv1 + p.pre[(size_t)b * 2048 + jA + 1];
        }
        __syncthreads();
        if (tid < 32) {
            int b = tid & 15, uu = tid >> 4;
            int u = u0 + uu;
            float gi = sigmoidf_(gsm[uu][0][b]);
            float gf = sigmoidf_(gsm[uu][1][b]);
            float gg = tanhf(gsm[uu][2][b]);
            float go = sigmoidf_(gsm[uu][3][b]);
            float c = gf * p.cr0[b * 512 + u] + gi * gg;
            crR = c;
            stA(p.hrb0 + b * 512 + u, go * tanhf(c));
        }
        ++tg; barArrive(p.slots, sidx, tg); gridWait(p.slots, tg);
    }

    for (int t = 0; t < TT; ++t) {
        const float* hrcur  = (t & 1) ? p.hrb1 : p.hrb0;
        float*       hrnext = (t & 1) ? p.hrb0 : p.hrb1;
        const float* hwprev = (t == 0) ? p.hw0 : (((t - 1) & 1) ? p.hwb1 : p.hwb0);
        float*       hwnext = (t & 1) ? p.hwb1 : p.hwb0;

        // ---- stage hr_t and hw_{t-1} into LDS via 8B relaxed atomic loads
        // (same per-thread-contiguous addressing as r11, half the transactions)
        {
            #pragma unroll
            for (int q = 0; q < 8; ++q) {
                int idx = q * 1024 + tid * 4;
                float2 a0 = ldA2(hrcur + idx);
                float2 a1 = ldA2(hrcur + idx + 2);
                float2 b0 = ldA2(hwprev + idx);
                float2 b1 = ldA2(hwprev + idx + 2);
                ((float4*)actH)[q * 256 + tid] = make_float4(a0.x, a0.y, a1.x, a1.y);
                ((float4*)actW)[q * 256 + tid] = make_float4(b0.x, b0.y, b1.x, b1.y);
            }
        }
        __syncthreads();

        // ========= stage A: deferred M update (local z) + sim + online partials
        {
            f8 h = ld8s(actH + bM * 512, lane);
            f8 w8 = {};
            if (t > 0) w8 = ld8s(actW + bM * 512, lane);
            float mx = -3.0e38f, ssum = 0.f;
            f8 macc = {};
            #pragma unroll
            for (int ii = 0; ii < 8; ++ii) {
                int rl = wv * 8 + ii;
                float4* mp0 = (float4*)&Mlds[rl][lane * 4];
                float4* mp1 = (float4*)&Mlds[rl][256 + lane * 4];
                f8 m; m.a = *mp0; m.b = *mp1;
                if (t > 0) {
                    float zf = 1.0f - __expf(simL[rl] - mxK) * sumInvK;
                    upd8(m, w8, zf);
                    *mp0 = m.a; *mp1 = m.b;
                }
                float s = wave_sum(dot8(m, h));
                float nmx = fmaxf(mx, s);
                float sc = __expf(mx - nmx);
                float wgt = __expf(s - nmx);
                fmaacc8(macc, sc, m, wgt);
                ssum = ssum * sc + wgt;
                mx = nmx;
                if (lane == 0) simL[rl] = s;
            }
            if (lane == 0) { smx4[wv] = mx; ssh4[wv] = ssum; }
            __syncthreads();
            float MXb = fmaxf(fmaxf(smx4[0], smx4[1]), fmaxf(smx4[2], smx4[3]));
            float sc2 = __expf(mx - MXb);
            float* d0 = &smacc[wv][lane * 4];
            float* d1 = &smacc[wv][256 + lane * 4];
            d0[0] = macc.a.x * sc2; d0[1] = macc.a.y * sc2;
            d0[2] = macc.a.z * sc2; d0[3] = macc.a.w * sc2;
            d1[0] = macc.b.x * sc2; d1[1] = macc.b.y * sc2;
            d1[2] = macc.b.z * sc2; d1[3] = macc.b.w * sc2;
            __syncthreads();
            {
                int r2 = tid * 2;       // 256 threads x 2 floats = 512
                float s0 = smacc[0][r2] + smacc[1][r2] + smacc[2][r2] + smacc[3][r2];
                float s1 = smacc[0][r2 + 1] + smacc[1][r2 + 1]
                         + smacc[2][r2 + 1] + smacc[3][r2 + 1];
                stA2(&p.mpart[(size_t)(kb * 8 + w2) * 512 + r2], s0, s1);
            }
            if (tid == 0) {
                float sB = ssh4[0] * __expf(smx4[0] - MXb)
                         + ssh4[1] * __expf(smx4[1] - MXb)
                         + ssh4[2] * __expf(smx4[2] - MXb)
                         + ssh4[3] * __expf(smx4[3] - MXb);
                stA(&p.mxpart[kb * 8 + w2], MXb);
                stA(&p.sumpart[kb * 8 + w2], sB);
            }
        }
        // ========= stage A2: read-LSTM gates for t+1 (LDS activations)
        if (t < 63) {
            float gv0 = gatedotL(actH, wR0, lane);
            float gv1 = gatedotL(actH, wR1, lane);
            if ((lane & 3) == 0) {
                int b = (lane >> 2) & 15;
                gsm[0][wv][b] = gv0 + p.pre[(size_t)((t + 1) * 16 + b) * 2048 + jA];
                gsm[1][wv][b] = gv1 + p.pre[(size_t)((t + 1) * 16 + b) * 2048 + jA + 1];
            }
            __syncthreads();
            if (tid < 32) {
                int b = tid & 15, uu = tid >> 4;
                int u = u0 + uu;
                float gi = sigmoidf_(gsm[uu][0][b]);
                float gf = sigmoidf_(gsm[uu][1][b]);
                float gg = tanhf(gsm[uu][2][b]);
                float go = sigmoidf_(gsm[uu][3][b]);
                float c = gf * crR + gi * gg;
                crR = c;
                stA(hrnext + b * 512 + u, go * tanhf(c));
            }
        }

        // ========= stage B-lite: group (k,b) softmax stats + mbuf slice
        ++tg; barArrive(p.slots, sidx, tg); groupWait(p.slots, gbase, tg);
        {
            float mxp[8];
            #pragma unroll
            for (int w3 = 0; w3 < 8; ++w3) mxp[w3] = ldA(&p.mxpart[kb * 8 + w3]);
            float MX = -3.0e38f;
            #pragma unroll
            for (int w3 = 0; w3 < 8; ++w3) MX = fmaxf(MX, mxp[w3]);
            float SUM = 0.f;
            #pragma unroll
            for (int w3 = 0; w3 < 8; ++w3)
                SUM += ldA(&p.sumpart[kb * 8 + w3]) * __expf(mxp[w3] - MX);
            mxK = MX;
            sumInvK = 1.0f / SUM;
            if (tid < 32) {
                int r2 = w2 * 64 + tid * 2;
                float a0 = 0.f, a1 = 0.f;
                #pragma unroll
                for (int w3 = 0; w3 < 8; ++w3) {
                    float cf = __expf(mxp[w3] - MX);
                    float2 v2 = ldA2(&p.mpart[(size_t)(kb * 8 + w3) * 512 + r2]);
                    a0 += cf * v2.x;
                    a1 += cf * v2.y;
                }
                stA2(&p.mbuf[(size_t)kb * 512 + r2], a0 * sumInvK, a1 * sumInvK);
            }
        }
        ++tg; barArrive(p.slots, sidx, tg); gridWait(p.slots, tg);

        // ========= stage C: comppre GEMV + hoisted vh = hw_prev . Whh_w
        float vh0, vh1;
        {
            vh0 = gatedotL(actW, wW0, lane);
            vh1 = gatedotL(actW, wW1, lane);
        }
        {
            float v;
            f8 A[16];
            if (part == 0) {
                v = gatedotL(actH, wC0, lane);
                ldactsA2(A, p.mbuf, lane);
                v += gatedotR(A, wC1, lane);
            } else {
                ldactsA2(A, p.mbuf + 16 * 512, lane);
                v = gatedotR(A, wC0, lane);
            }
            if ((lane & 3) == 0) {
                int b = (lane >> 2) & 15;
                cc[jj][part][b] = v;
            }
            __syncthreads();
            if (tid < 32) {
                int b = tid & 15, jj2 = tid >> 4;
                stA(&p.comppre[b * 512 + (u0 + jj2)],
                    cc[jj2][0][b] + cc[jj2][1][b] + bcsh[jj2]);
            }
        }
        ++tg; barArrive(p.slots, sidx, tg); gridWait(p.slots, tg);

        // ========= stage D: cooperative softmax -> E (coalesced, conflict-
        // free) in actH overlay; write-LSTM gates from LDS E
        {
            float v[8][4];
            #pragma unroll
            for (int k = 0; k < 8; ++k) {
                int idx = k * 1024 + tid * 4;
                float2 u0v = ldA2(p.comppre + idx);
                float2 u1v = ldA2(p.comppre + idx + 2);
                v[k][0] = u0v.x; v[k][1] = u0v.y; v[k][2] = u1v.x; v[k][3] = u1v.y;
            }
            const int bpar = wv >> 1;     // tid>>7
            #pragma unroll
            for (int k = 0; k < 8; ++k) {
                float mk = fmaxf(fmaxf(v[k][0], v[k][1]), fmaxf(v[k][2], v[k][3]));
                mk = wave_max(mk);
                if (lane == 0) wmx[2 * k + bpar][wv & 1] = mk;
            }
            __syncthreads();                 // actH (hr) reads all done
            float4* Eld4 = (float4*)actH;
            #pragma unroll
            for (int k = 0; k < 8; ++k) {
                float mxb = fmaxf(wmx[2 * k + bpar][0], wmx[2 * k + bpar][1]);
                float e0 = __expf(v[k][0] - mxb), e1 = __expf(v[k][1] - mxb);
                float e2 = __expf(v[k][2] - mxb), e3 = __expf(v[k][3] - mxb);
                Eld4[k * 256 + tid] = make_float4(e0, e1, e2, e3);
                float sv = wave_sum(e0 + e1 + e2 + e3);
                if (lane == 0) wsm[2 * k + bpar][wv & 1] = sv;
            }
            __syncthreads();
            float ti0 = gatedotL(actH, wI0, lane);
            float ti1 = gatedotL(actH, wI1, lane);
            if ((lane & 3) == 0) {
                int bb = (lane >> 2) & 15;
                float siv = 1.0f / (wsm[bb][0] + wsm[bb][1]);
                gsm[0][wv][bb] = ti0 * siv + vh0 + bw0;
                gsm[1][wv][bb] = ti1 * siv + vh1 + bw1;
            }
            __syncthreads();
            if (tid < 32) {
                int bb = tid & 15, uu = tid >> 4;
                int u = u0 + uu;
                float gi = sigmoidf_(gsm[uu][0][bb]);
                float gf = sigmoidf_(gsm[uu][1][bb]);
                float gg = tanhf(gsm[uu][2][bb]);
                float go = sigmoidf_(gsm[uu][3][bb]);
                float c = gf * cwR + gi * gg;
                cwR = c;
                float h = go * tanhf(c);
                stA(hwnext + bb * 512 + u, h);
                p.outputs[(size_t)t * 8192 + bb * 512 + u] = h;
            }
        }
        ++tg; barArrive(p.slots, sidx, tg); gridWait(p.slots, tg);
    }

    // ---- epilogue: final deferred M update with (z_63, hw_63 = hwb1);
    //      write LDS M -> Mf; flush cr/cw registers to d_out
    {
        f8 w8 = ld8sA2(p.hwb1 + (size_t)bM * 512, lane);
        #pragma unroll
        for (int ii = 0; ii < 8; ++ii) {
            int rl = wv * 8 + ii;
            float zf = 1.0f - __expf(simL[rl] - mxK) * sumInvK;
            f8 m;
            m.a = *(float4*)&Mlds[rl][lane * 4];
            m.b = *(float4*)&Mlds[rl][256 + lane * 4];
            upd8(m, w8, zf);
            st8s(p.Mw + (size_t)(rowG + rl) * 512, m, lane);
        }
        if (tid < 32) {
            int b = tid & 15, uu = tid >> 4;
            int u = u0 + uu;
            p.crS[b * 512 + u] = crR;
            p.cwS[b * 512 + u] = cwR;
        }
    }
}

extern "C" void kernel_launch(void* const* d_in, const int* in_sizes, int n_in,
                              void* d_out, int out_size, void* d_ws, size_t ws_size,
                              hipStream_t stream) {
    const float* emb   = (const float*)d_in[0];
    const float* hr0   = (const float*)d_in[1];
    const float* cr0   = (const float*)d_in[2];
    const float* hw0   = (const float*)d_in[3];
    const float* cw0   = (const float*)d_in[4];
    const float* io    = (const float*)d_in[5];
    const float* M0    = (const float*)d_in[6];
    const float* Wih_r = (const float*)d_in[7];
    const float* bih_r = (const float*)d_in[9];
    const float* bhh_r = (const float*)d_in[10];

    float* out = (float*)d_out;
    float* outputs = out;                    // [64][16][512]
    float* hrS1 = out + 524288;              // hr slot = hr parity-1 buf
    float* crS  = out + 532480;
    float* hwS1 = out + 540672;              // hw slot = hw parity-1 buf
    float* cwS  = out + 548864;
    float* Mw   = out + 557056;              // Mf (written once at epilogue)

    float* ws = (float*)d_ws;
    float* pre     = ws;                     // 1024*2048
    float* mbuf    = ws + 2097152;           // 32*512
    float* comppre = mbuf + 16384;           // 16*512
    float* hrB0    = comppre + 8192;         // hr parity 0
    float* hwB0    = hrB0 + 8192;            // hw parity 0
    float* mpart   = hwB0 + 8192;            // 256*512
    float* mxpart  = mpart + 131072;         // 256
    float* sumpart = mxpart + 256;           // 256
    unsigned* slots = (unsigned*)(sumpart + 256); // 256 uints

    (void)hipMemsetAsync(slots, 0, 256 * sizeof(unsigned), stream);

    k_pre<<<dim3(32, 16), 256, 0, stream>>>(emb, io, Wih_r, bih_r, bhh_r, pre);

    P p;
    p.pre = pre;
    p.Whh_r = (const float*)d_in[8];
    p.Wc    = (const float*)d_in[11];
    p.bc    = (const float*)d_in[12];
    p.Wih_w = (const float*)d_in[13];
    p.Whh_w = (const float*)d_in[14];
    p.bih_w = (const float*)d_in[15];
    p.bhh_w = (const float*)d_in[16];
    p.hr0 = hr0; p.cr0 = cr0; p.hw0 = hw0; p.cw0 = cw0; p.M0 = M0;
    p.mbuf = mbuf; p.comppre = comppre;
    p.mpart = mpart; p.mxpart = mxpart; p.sumpart = sumpart;
    p.hrb0 = hrB0; p.hrb1 = hrS1; p.crS = crS;
    p.hwb0 = hwB0; p.hwb1 = hwS1; p.cwS = cwS;
    p.outputs = outputs; p.Mw = Mw;
    p.slots = slots;

    k_persist<<<NBLK, 256, 0, stream>>>(p);
}

// Round 14
// 1903.067 us; speedup vs baseline: 2.5721x; 1.2101x over previous
//
#include <hip/hip_runtime.h>
#include <math.h>

#define RR 512
#define BB 16
#define TT 64
#define KC 2
#define NN 256
#define NBLK 256

__device__ __forceinline__ float sigmoidf_(float x) {
    return 1.0f / (1.0f + __expf(-x));
}
__device__ __forceinline__ float wave_sum(float v) {
    #pragma unroll
    for (int off = 32; off > 0; off >>= 1) v += __shfl_xor(v, off, 64);
    return v;
}
__device__ __forceinline__ float wave_max(float v) {
    #pragma unroll
    for (int off = 32; off > 0; off >>= 1) v = fmaxf(v, __shfl_xor(v, off, 64));
    return v;
}

// ---- relaxed agent-scope atomic ops (MALL-coherent, no cache fences) ----
__device__ __forceinline__ float ldA(const float* p) {
    return __hip_atomic_load(p, __ATOMIC_RELAXED, __HIP_MEMORY_SCOPE_AGENT);
}
__device__ __forceinline__ void stA(float* p, float v) {
    __hip_atomic_store(p, v, __ATOMIC_RELAXED, __HIP_MEMORY_SCOPE_AGENT);
}
__device__ __forceinline__ unsigned ldU(const unsigned* p) {
    return __hip_atomic_load(p, __ATOMIC_RELAXED, __HIP_MEMORY_SCOPE_AGENT);
}
__device__ __forceinline__ void stU(unsigned* p, unsigned v) {
    __hip_atomic_store(p, v, __ATOMIC_RELAXED, __HIP_MEMORY_SCOPE_AGENT);
}
__device__ __forceinline__ float2 ldA2(const float* p) {
    unsigned long long v = __hip_atomic_load((const unsigned long long*)p,
                                             __ATOMIC_RELAXED, __HIP_MEMORY_SCOPE_AGENT);
    float2 r;
    r.x = __uint_as_float((unsigned)v);
    r.y = __uint_as_float((unsigned)(v >> 32));
    return r;
}
__device__ __forceinline__ void stA2(float* p, float x, float y) {
    unsigned long long v = ((unsigned long long)__float_as_uint(y) << 32)
                         | (unsigned long long)__float_as_uint(x);
    __hip_atomic_store((unsigned long long*)p, v, __ATOMIC_RELAXED,
                       __HIP_MEMORY_SCOPE_AGENT);
}

// ---- 8x coherent 16B loads, waitcnt INSIDE the asm block: outputs are
// defined when the asm completes, so no issue->wait live-range window for
// regalloc to spill/copy an unwritten register (the r10 failure mode).
// sc0 sc1 bypasses L1/L2 -> MALL-coherent, same semantics as relaxed agent
// atomics (stronger scope), no cache maintenance.
#define LDG8(d0,d1,d2,d3,d4,d5,d6,d7, q0,q1,q2,q3,q4,q5,q6,q7)      \
    asm volatile(                                                     \
        "global_load_dwordx4 %0, %8, off sc0 sc1\n\t"                \
        "global_load_dwordx4 %1, %9, off sc0 sc1\n\t"                \
        "global_load_dwordx4 %2, %10, off sc0 sc1\n\t"               \
        "global_load_dwordx4 %3, %11, off sc0 sc1\n\t"               \
        "global_load_dwordx4 %4, %12, off sc0 sc1\n\t"               \
        "global_load_dwordx4 %5, %13, off sc0 sc1\n\t"               \
        "global_load_dwordx4 %6, %14, off sc0 sc1\n\t"               \
        "global_load_dwordx4 %7, %15, off sc0 sc1\n\t"               \
        "s_waitcnt vmcnt(0)"                                          \
        : "=&v"(d0), "=&v"(d1), "=&v"(d2), "=&v"(d3),                 \
          "=&v"(d4), "=&v"(d5), "=&v"(d6), "=&v"(d7)                  \
        : "v"(q0), "v"(q1), "v"(q2), "v"(q3),                         \
          "v"(q4), "v"(q5), "v"(q6), "v"(q7)                          \
        : "memory")

struct f8 { float4 a, b; };
// split-slice mapping: lane's 8 floats of a 512-row = [lane*4,+4) and
// [256+lane*4,+4). Conflict-free LDS b128. Used for LDS-resident operands.
__device__ __forceinline__ f8 ld8s(const float* row, int lane) {
    f8 r;
    r.a = *(const float4*)(row + lane * 4);
    r.b = *(const float4*)(row + 256 + lane * 4);
    return r;
}
__device__ __forceinline__ void st8s(float* row, const f8& v, int lane) {
    *(float4*)(row + lane * 4) = v.a;
    *(float4*)(row + 256 + lane * 4) = v.b;
}
__device__ __forceinline__ f8 ld8sA2(const float* row, int lane) {
    float2 t0 = ldA2(row + lane * 4);
    float2 t1 = ldA2(row + lane * 4 + 2);
    float2 t2 = ldA2(row + 256 + lane * 4);
    float2 t3 = ldA2(row + 256 + lane * 4 + 2);
    f8 r;
    r.a = make_float4(t0.x, t0.y, t1.x, t1.y);
    r.b = make_float4(t2.x, t2.y, t3.x, t3.y);
    return r;
}
__device__ __forceinline__ float dot8(const f8& x, const f8& y) {
    return x.a.x*y.a.x + x.a.y*y.a.y + x.a.z*y.a.z + x.a.w*y.a.w
         + x.b.x*y.b.x + x.b.y*y.b.y + x.b.z*y.b.z + x.b.w*y.b.w;
}
// inline function, NOT a macro (macro param `w` collides with float4::w)
__device__ __forceinline__ void upd8(f8& m, const f8& u, float zf) {
    m.a.x = zf * (m.a.x + u.a.x); m.a.y = zf * (m.a.y + u.a.y);
    m.a.z = zf * (m.a.z + u.a.z); m.a.w = zf * (m.a.w + u.a.w);
    m.b.x = zf * (m.b.x + u.b.x); m.b.y = zf * (m.b.y + u.b.y);
    m.b.z = zf * (m.b.z + u.b.z); m.b.w = zf * (m.b.w + u.b.w);
}
__device__ __forceinline__ void fmaacc8(f8& acc, float sc, const f8& m, float wgt) {
    acc.a.x = acc.a.x*sc + wgt*m.a.x; acc.a.y = acc.a.y*sc + wgt*m.a.y;
    acc.a.z = acc.a.z*sc + wgt*m.a.z; acc.a.w = acc.a.w*sc + wgt*m.a.w;
    acc.b.x = acc.b.x*sc + wgt*m.b.x; acc.b.y = acc.b.y*sc + wgt*m.b.y;
    acc.b.z = acc.b.z*sc + wgt*m.b.z; acc.b.w = acc.b.w*sc + wgt*m.b.w;
}

// Payload-halving butterfly: p[0..15] per-b partials across 64 lanes ->
// each lane returns the full sum for b = (lane>>2)&15.
__device__ __forceinline__ float reduce16(float* p, int lane) {
    float q[8];
    {
        bool hi = (lane & 32) != 0;
        #pragma unroll
        for (int i = 0; i < 8; ++i) {
            float snd = hi ? p[i] : p[i + 8];
            float r = __shfl_xor(snd, 32, 64);
            q[i] = (hi ? p[i + 8] : p[i]) + r;
        }
    }
    float s4[4];
    {
        bool hi = (lane & 16) != 0;
        #pragma unroll
        for (int i = 0; i < 4; ++i) {
            float snd = hi ? q[i] : q[i + 4];
            float r = __shfl_xor(snd, 16, 64);
            s4[i] = (hi ? q[i + 4] : q[i]) + r;
        }
    }
    float d2[2];
    {
        bool hi = (lane & 8) != 0;
        #pragma unroll
        for (int i = 0; i < 2; ++i) {
            float snd = hi ? s4[i] : s4[i + 2];
            float r = __shfl_xor(snd, 8, 64);
            d2[i] = (hi ? s4[i + 2] : s4[i]) + r;
        }
    }
    float v;
    {
        bool hi = (lane & 4) != 0;
        float snd = hi ? d2[0] : d2[1];
        float r = __shfl_xor(snd, 4, 64);
        v = (hi ? d2[1] : d2[0]) + r;
    }
    v += __shfl_xor(v, 2, 64);
    v += __shfl_xor(v, 1, 64);
    return v;
}

__device__ __forceinline__ float gatedotR(const f8* A, const f8& w, int lane) {
    float p[16];
    #pragma unroll
    for (int b = 0; b < 16; ++b) p[b] = dot8(A[b], w);
    return reduce16(p, lane);
}
// gatedot streaming rows from LDS (low register pressure, block-local)
__device__ __forceinline__ float gatedotL(const float* act, const f8& w, int lane) {
    float p[16];
    #pragma unroll
    for (int b = 0; b < 16; ++b) {
        f8 r = ld8s(act + b * 512, lane);
        p[b] = dot8(r, w);
    }
    return reduce16(p, lane);
}
__device__ __forceinline__ void ldacts(f8* A, const float* act, int lane) {
    #pragma unroll
    for (int b = 0; b < 16; ++b) A[b] = ld8s(act + b * 512, lane);
}

// ---- store-slot barrier (RMW-free, fence-free). slots[256] hold each
// block's monotonically increasing generation. Arrival = per-wave vmcnt
// drain -> syncthreads -> one relaxed store. Wait = wave-0 lanes poll until
// __all(slot >= tgt). No release hop, no counter reset, no ABA (monotone).
__device__ __forceinline__ void barArrive(unsigned* slots, int sidx, unsigned tgt) {
    asm volatile("s_waitcnt vmcnt(0)" ::: "memory");
    __syncthreads();
    if (threadIdx.x == 0) stU(slots + sidx, tgt);
}
__device__ __forceinline__ void gridWait(unsigned* slots, unsigned tgt) {
    if (threadIdx.x < 64) {
        const unsigned* base = slots + threadIdx.x * 4;
        for (;;) {
            bool ok = (ldU(base + 0) >= tgt) & (ldU(base + 1) >= tgt)
                    & (ldU(base + 2) >= tgt) & (ldU(base + 3) >= tgt);
            if (__all(ok)) break;
            __builtin_amdgcn_s_sleep(1);
        }
    }
    __syncthreads();
}
__device__ __forceinline__ void groupWait(unsigned* slots, int gbase, unsigned tgt) {
    if (threadIdx.x < 64) {
        const unsigned* ps = slots + gbase + (threadIdx.x & 7);
        for (;;) {
            bool ok = ldU(ps) >= tgt;
            if (__all(ok)) break;
            __builtin_amdgcn_s_sleep(1);
        }
    }
    __syncthreads();
}

// ---------------------------------------------------------------------------
// k_pre: pre[t*16+b][j] = [emb|io] @ Wih_r^T + bih_r + bhh_r   (proven r1-r13)
// ---------------------------------------------------------------------------
__global__ void k_pre(const float* __restrict__ emb, const float* __restrict__ io,
                      const float* __restrict__ Wih, const float* __restrict__ bih,
                      const float* __restrict__ bhh, float* __restrict__ pre)
{
    __shared__ float As[16][65];
    __shared__ float Bs[16][65];
    int tid = threadIdx.x;
    int row0 = blockIdx.y * 64;
    int col0 = blockIdx.x * 64;
    int ty = tid >> 4, tx = tid & 15;
    float acc[4][4] = {};
    int lr = tid >> 2;
    int lk4 = (tid & 3) * 4;
    for (int k0 = 0; k0 < 1024; k0 += 16) {
        int grow = row0 + lr;
        int b = grow & 15;
        #pragma unroll
        for (int q = 0; q < 4; ++q) {
            int k = k0 + lk4 + q;
            float v = (k < RR) ? emb[(size_t)grow * RR + k]
                               : io[(size_t)b * RR + (k - RR)];
            As[lk4 + q][lr] = v;
        }
        #pragma unroll
        for (int q = 0; q < 4; ++q) {
            int k = k0 + lk4 + q;
            Bs[lk4 + q][lr] = Wih[(size_t)(col0 + lr) * 1024 + k];
        }
        __syncthreads();
        #pragma unroll
        for (int kk = 0; kk < 16; ++kk) {
            float a[4], bbv[4];
            #pragma unroll
            for (int i = 0; i < 4; ++i) a[i] = As[kk][ty * 4 + i];
            #pragma unroll
            for (int j = 0; j < 4; ++j) bbv[j] = Bs[kk][tx * 4 + j];
            #pragma unroll
            for (int i = 0; i < 4; ++i)
                #pragma unroll
                for (int j = 0; j < 4; ++j)
                    acc[i][j] += a[i] * bbv[j];
        }
        __syncthreads();
    }
    #pragma unroll
    for (int i = 0; i < 4; ++i) {
        int grow = row0 + ty * 4 + i;
        #pragma unroll
        for (int j = 0; j < 4; ++j) {
            int gcol = col0 + tx * 4 + j;
            pre[(size_t)grow * 2048 + gcol] = acc[i][j] + bih[gcol] + bhh[gcol];
        }
    }
}

struct P {
    const float *pre, *Whh_r, *Wc, *bc, *Wih_w, *Whh_w, *bih_w, *bhh_w;
    const float *hr0, *cr0, *hw0, *cw0, *M0;
    float *mbuf, *comppre, *mpart, *mxpart, *sumpart;
    float *hrb0, *hrb1, *crS, *hwb0, *hwb1, *cwS;
    float *outputs, *Mw;
    unsigned *slots;
};

// ---------------------------------------------------------------------------
// Persistent kernel: 64-step recurrence. M + staged activations in LDS;
// weights + cr/cw in registers; store-slot barriers; bulk cross-block reads
// via coherent dwordx4 (waitcnt in-asm); stores via relaxed agent atomics.
// ---------------------------------------------------------------------------
__global__ void __launch_bounds__(256, 1) k_persist(P p)
{
    const int tid = threadIdx.x;
    const int bid = blockIdx.x;
    const int wv = tid >> 6;
    const int lane = tid & 63;
    const int u0 = bid * 2;
    const int kb = (bid & 7) * 4 + (bid >> 6);   // (k,b) group
    const int w2 = (bid >> 3) & 7;               // slot within group
    const int bM = kb & 15;
    const int rowG = kb * 256 + w2 * 32;
    const int sidx = kb * 8 + w2;                // barrier slot (group-contig)
    const int gbase = kb * 8;

    __shared__ float Mlds[32][512];       // 64 KB
    __shared__ float actH[16 * 512];      // 32 KB: hr_t staged; E overlay in D
    __shared__ float actW[16 * 512];      // 32 KB: hw_{t-1} staged
    __shared__ float smacc[4][512];       // 8 KB
    __shared__ float smx4[4], ssh4[4];
    __shared__ float simL[32];
    __shared__ float gsm[2][4][16];
    __shared__ float cc[2][2][16];
    __shared__ float wmx[16][2], wsm[16][2];
    __shared__ float bcsh[2];

    unsigned tg = 0;
    float mxK = 0.f, sumInvK = 0.f;
    float crR = 0.f, cwR = 0.f;

    // ---- register-resident weight slices (split-slice mapping)
    const int jA = wv * 512 + u0;
    const f8 wR0 = ld8s(p.Whh_r + (size_t)jA * 512, lane);
    const f8 wR1 = ld8s(p.Whh_r + (size_t)(jA + 1) * 512, lane);
    const f8 wW0 = ld8s(p.Whh_w + (size_t)jA * 512, lane);
    const f8 wW1 = ld8s(p.Whh_w + (size_t)(jA + 1) * 512, lane);
    const f8 wI0 = ld8s(p.Wih_w + (size_t)jA * 512, lane);
    const f8 wI1 = ld8s(p.Wih_w + (size_t)(jA + 1) * 512, lane);
    const float bw0 = p.bih_w[jA] + p.bhh_w[jA];
    const float bw1 = p.bih_w[jA + 1] + p.bhh_w[jA + 1];
    const int jj = wv >> 1, part = wv & 1;
    const int jC = u0 + jj;
    f8 wC0, wC1 = {};
    if (part == 0) {
        wC0 = ld8s(p.Wc + (size_t)jC * 1536, lane);
        wC1 = ld8s(p.Wc + (size_t)jC * 1536 + 512, lane);
    } else {
        wC0 = ld8s(p.Wc + (size_t)jC * 1536 + 1024, lane);
    }
    if (tid < 2) bcsh[tid] = p.bc[u0 + tid];
    if (tid < 32) cwR = p.cw0[(tid & 15) * 512 + u0 + (tid >> 4)];

    // ---- load this block's M rows: global M0 -> LDS (once)
    {
        const float4* src = (const float4*)(p.M0 + (size_t)rowG * 512);
        float4* dst = (float4*)&Mlds[0][0];
        #pragma unroll 4
        for (int idx = tid; idx < 32 * 128; idx += 256)
            dst[idx] = src[idx];
    }

    // ---- prologue: read-LSTM step 0 -> hr_0 (hrb0), cr_0 (register)
    {
        f8 A[16]; ldacts(A, p.hr0, lane);
        float gv0 = gatedotR(A, wR0, lane);
        float gv1 = gatedotR(A, wR1, lane);
        if ((lane & 3) == 0) {
            int b = (lane >> 2) & 15;
            gsm[0][wv][b] = gv0 + p.pre[(size_t)b * 2048 + jA];
            gsm[1][wv][b] = gv1 + p.pre[(size_t)b * 2048 + jA + 1];
        }
        __syncthreads();
        if (tid < 32) {
            int b = tid & 15, uu = tid >> 4;
            int u = u0 + uu;
            float gi = sigmoidf_(gsm[uu][0][b]);
            float gf = sigmoidf_(gsm[uu][1][b]);
            float gg = tanhf(gsm[uu][2][b]);
            float go = sigmoidf_(gsm[uu][3][b]);
            float c = gf * p.cr0[b * 512 + u] + gi * gg;
            crR = c;
            stA(p.hrb0 + b * 512 + u, go * tanhf(c));
        }
        ++tg; barArrive(p.slots, sidx, tg); gridWait(p.slots, tg);
    }

    for (int t = 0; t < TT; ++t) {
        const float* hrcur  = (t & 1) ? p.hrb1 : p.hrb0;
        float*       hrnext = (t & 1) ? p.hrb0 : p.hrb1;
        const float* hwprev = (t == 0) ? p.hw0 : (((t - 1) & 1) ? p.hwb1 : p.hwb0);
        float*       hwnext = (t & 1) ? p.hwb1 : p.hwb0;

        // ---- stage hr_t and hw_{t-1} into LDS: coherent dwordx4 batches
        {
            float4 ha[8], wa[8];
            const float* hsrc = hrcur + tid * 4;
            const float* wsrc = hwprev + tid * 4;
            LDG8(ha[0], ha[1], ha[2], ha[3], ha[4], ha[5], ha[6], ha[7],
                 hsrc, hsrc + 1024, hsrc + 2048, hsrc + 3072,
                 hsrc + 4096, hsrc + 5120, hsrc + 6144, hsrc + 7168);
            LDG8(wa[0], wa[1], wa[2], wa[3], wa[4], wa[5], wa[6], wa[7],
                 wsrc, wsrc + 1024, wsrc + 2048, wsrc + 3072,
                 wsrc + 4096, wsrc + 5120, wsrc + 6144, wsrc + 7168);
            #pragma unroll
            for (int q = 0; q < 8; ++q) {
                ((float4*)actH)[q * 256 + tid] = ha[q];
                ((float4*)actW)[q * 256 + tid] = wa[q];
            }
        }
        __syncthreads();

        // ========= stage A: deferred M update (local z) + sim + online partials
        {
            f8 h = ld8s(actH + bM * 512, lane);
            f8 w8 = {};
            if (t > 0) w8 = ld8s(actW + bM * 512, lane);
            float mx = -3.0e38f, ssum = 0.f;
            f8 macc = {};
            #pragma unroll
            for (int ii = 0; ii < 8; ++ii) {
                int rl = wv * 8 + ii;
                float4* mp0 = (float4*)&Mlds[rl][lane * 4];
                float4* mp1 = (float4*)&Mlds[rl][256 + lane * 4];
                f8 m; m.a = *mp0; m.b = *mp1;
                if (t > 0) {
                    float zf = 1.0f - __expf(simL[rl] - mxK) * sumInvK;
                    upd8(m, w8, zf);
                    *mp0 = m.a; *mp1 = m.b;
                }
                float s = wave_sum(dot8(m, h));
                float nmx = fmaxf(mx, s);
                float sc = __expf(mx - nmx);
                float wgt = __expf(s - nmx);
                fmaacc8(macc, sc, m, wgt);
                ssum = ssum * sc + wgt;
                mx = nmx;
                if (lane == 0) simL[rl] = s;
            }
            if (lane == 0) { smx4[wv] = mx; ssh4[wv] = ssum; }
            __syncthreads();
            float MXb = fmaxf(fmaxf(smx4[0], smx4[1]), fmaxf(smx4[2], smx4[3]));
            float sc2 = __expf(mx - MXb);
            float* d0 = &smacc[wv][lane * 4];
            float* d1 = &smacc[wv][256 + lane * 4];
            d0[0] = macc.a.x * sc2; d0[1] = macc.a.y * sc2;
            d0[2] = macc.a.z * sc2; d0[3] = macc.a.w * sc2;
            d1[0] = macc.b.x * sc2; d1[1] = macc.b.y * sc2;
            d1[2] = macc.b.z * sc2; d1[3] = macc.b.w * sc2;
            __syncthreads();
            {
                int r2 = tid * 2;       // 256 threads x 2 floats = 512
                float s0 = smacc[0][r2] + smacc[1][r2] + smacc[2][r2] + smacc[3][r2];
                float s1 = smacc[0][r2 + 1] + smacc[1][r2 + 1]
                         + smacc[2][r2 + 1] + smacc[3][r2 + 1];
                stA2(&p.mpart[(size_t)(kb * 8 + w2) * 512 + r2], s0, s1);
            }
            if (tid == 0) {
                float sB = ssh4[0] * __expf(smx4[0] - MXb)
                         + ssh4[1] * __expf(smx4[1] - MXb)
                         + ssh4[2] * __expf(smx4[2] - MXb)
                         + ssh4[3] * __expf(smx4[3] - MXb);
                stA(&p.mxpart[kb * 8 + w2], MXb);
                stA(&p.sumpart[kb * 8 + w2], sB);
            }
        }
        // ========= stage A2: read-LSTM gates for t+1 (LDS activations)
        if (t < 63) {
            float gv0 = gatedotL(actH, wR0, lane);
            float gv1 = gatedotL(actH, wR1, lane);
            if ((lane & 3) == 0) {
                int b = (lane >> 2) & 15;
                gsm[0][wv][b] = gv0 + p.pre[(size_t)((t + 1) * 16 + b) * 2048 + jA];
                gsm[1][wv][b] = gv1 + p.pre[(size_t)((t + 1) * 16 + b) * 2048 + jA + 1];
            }
            __syncthreads();
            if (tid < 32) {
                int b = tid & 15, uu = tid >> 4;
                int u = u0 + uu;
                float gi = sigmoidf_(gsm[uu][0][b]);
                float gf = sigmoidf_(gsm[uu][1][b]);
                float gg = tanhf(gsm[uu][2][b]);
                float go = sigmoidf_(gsm[uu][3][b]);
                float c = gf * crR + gi * gg;
                crR = c;
                stA(hrnext + b * 512 + u, go * tanhf(c));
            }
        }

        // ========= stage B-lite: group (k,b) softmax stats + mbuf slice
        ++tg; barArrive(p.slots, sidx, tg); groupWait(p.slots, gbase, tg);
        {
            float mxp[8];
            #pragma unroll
            for (int w3 = 0; w3 < 8; ++w3) mxp[w3] = ldA(&p.mxpart[kb * 8 + w3]);
            float MX = -3.0e38f;
            #pragma unroll
            for (int w3 = 0; w3 < 8; ++w3) MX = fmaxf(MX, mxp[w3]);
            float SUM = 0.f;
            #pragma unroll
            for (int w3 = 0; w3 < 8; ++w3)
                SUM += ldA(&p.sumpart[kb * 8 + w3]) * __expf(mxp[w3] - MX);
            mxK = MX;
            sumInvK = 1.0f / SUM;
            if (tid < 32) {
                int r2 = w2 * 64 + tid * 2;
                float a0 = 0.f, a1 = 0.f;
                #pragma unroll
                for (int w3 = 0; w3 < 8; ++w3) {
                    float cf = __expf(mxp[w3] - MX);
                    float2 v2 = ldA2(&p.mpart[(size_t)(kb * 8 + w3) * 512 + r2]);
                    a0 += cf * v2.x;
                    a1 += cf * v2.y;
                }
                stA2(&p.mbuf[(size_t)kb * 512 + r2], a0 * sumInvK, a1 * sumInvK);
            }
        }
        ++tg; barArrive(p.slots, sidx, tg); gridWait(p.slots, tg);

        // ========= stage C: comppre GEMV + hoisted vh = hw_prev . Whh_w
        float vh0, vh1;
        {
            vh0 = gatedotL(actW, wW0, lane);
            vh1 = gatedotL(actW, wW1, lane);
        }
        {
            float v;
            f8 Am[16];
            const float* ms = p.mbuf + (part ? 16 * 512 : 0) + lane * 4;
            #pragma unroll
            for (int g = 0; g < 4; ++g) {
                const float* r0 = ms + (g * 4 + 0) * 512;
                const float* r1 = ms + (g * 4 + 1) * 512;
                const float* r2 = ms + (g * 4 + 2) * 512;
                const float* r3 = ms + (g * 4 + 3) * 512;
                LDG8(Am[g*4+0].a, Am[g*4+0].b, Am[g*4+1].a, Am[g*4+1].b,
                     Am[g*4+2].a, Am[g*4+2].b, Am[g*4+3].a, Am[g*4+3].b,
                     r0, r0 + 256, r1, r1 + 256, r2, r2 + 256, r3, r3 + 256);
            }
            if (part == 0) {
                v = gatedotL(actH, wC0, lane) + gatedotR(Am, wC1, lane);
            } else {
                v = gatedotR(Am, wC0, lane);
            }
            if ((lane & 3) == 0) {
                int b = (lane >> 2) & 15;
                cc[jj][part][b] = v;
            }
            __syncthreads();
            if (tid < 32) {
                int b = tid & 15, jj2 = tid >> 4;
                stA(&p.comppre[b * 512 + (u0 + jj2)],
                    cc[jj2][0][b] + cc[jj2][1][b] + bcsh[jj2]);
            }
        }
        ++tg; barArrive(p.slots, sidx, tg); gridWait(p.slots, tg);

        // ========= stage D: cooperative softmax -> E (coalesced, conflict-
        // free) in actH overlay; write-LSTM gates from LDS E
        {
            float4 v4[8];
            const float* cs = p.comppre + tid * 4;
            LDG8(v4[0], v4[1], v4[2], v4[3], v4[4], v4[5], v4[6], v4[7],
                 cs, cs + 1024, cs + 2048, cs + 3072,
                 cs + 4096, cs + 5120, cs + 6144, cs + 7168);
            const int bpar = wv >> 1;     // tid>>7
            #pragma unroll
            for (int k = 0; k < 8; ++k) {
                float mk = fmaxf(fmaxf(v4[k].x, v4[k].y), fmaxf(v4[k].z, v4[k].w));
                mk = wave_max(mk);
                if (lane == 0) wmx[2 * k + bpar][wv & 1] = mk;
            }
            __syncthreads();                 // actH (hr) reads all done
            float4* Eld4 = (float4*)actH;
            #pragma unroll
            for (int k = 0; k < 8; ++k) {
                float mxb = fmaxf(wmx[2 * k + bpar][0], wmx[2 * k + bpar][1]);
                float e0 = __expf(v4[k].x - mxb), e1 = __expf(v4[k].y - mxb);
                float e2 = __expf(v4[k].z - mxb), e3 = __expf(v4[k].w - mxb);
                Eld4[k * 256 + tid] = make_float4(e0, e1, e2, e3);
                float sv = wave_sum(e0 + e1 + e2 + e3);
                if (lane == 0) wsm[2 * k + bpar][wv & 1] = sv;
            }
            __syncthreads();
            float ti0 = gatedotL(actH, wI0, lane);
            float ti1 = gatedotL(actH, wI1, lane);
            if ((lane & 3) == 0) {
                int bb = (lane >> 2) & 15;
                float siv = 1.0f / (wsm[bb][0] + wsm[bb][1]);
                gsm[0][wv][bb] = ti0 * siv + vh0 + bw0;
                gsm[1][wv][bb] = ti1 * siv + vh1 + bw1;
            }
            __syncthreads();
            if (tid < 32) {
                int bb = tid & 15, uu = tid >> 4;
                int u = u0 + uu;
                float gi = sigmoidf_(gsm[uu][0][bb]);
                float gf = sigmoidf_(gsm[uu][1][bb]);
                float gg = tanhf(gsm[uu][2][bb]);
                float go = sigmoidf_(gsm[uu][3][bb]);
                float c = gf * cwR + gi * gg;
                cwR = c;
                float h = go * tanhf(c);
                stA(hwnext + bb * 512 + u, h);
                p.outputs[(size_t)t * 8192 + bb * 512 + u] = h;
            }
        }
        ++tg; barArrive(p.slots, sidx, tg); gridWait(p.slots, tg);
    }

    // ---- epilogue: final deferred M update with (z_63, hw_63 = hwb1);
    //      write LDS M -> Mf; flush cr/cw registers to d_out
    {
        f8 w8 = ld8sA2(p.hwb1 + (size_t)bM * 512, lane);
        #pragma unroll
        for (int ii = 0; ii < 8; ++ii) {
            int rl = wv * 8 + ii;
            float zf = 1.0f - __expf(simL[rl] - mxK) * sumInvK;
            f8 m;
            m.a = *(float4*)&Mlds[rl][lane * 4];
            m.b = *(float4*)&Mlds[rl][256 + lane * 4];
            upd8(m, w8, zf);
            st8s(p.Mw + (size_t)(rowG + rl) * 512, m, lane);
        }
        if (tid < 32) {
            int b = tid & 15, uu = tid >> 4;
            int u = u0 + uu;
            p.crS[b * 512 + u] = crR;
            p.cwS[b * 512 + u] = cwR;
        }
    }
}

extern "C" void kernel_launch(void* const* d_in, const int* in_sizes, int n_in,
                              void* d_out, int out_size, void* d_ws, size_t ws_size,
                              hipStream_t stream) {
    const float* emb   = (const float*)d_in[0];
    const float* hr0   = (const float*)d_in[1];
    const float* cr0   = (const float*)d_in[2];
    const float* hw0   = (const float*)d_in[3];
    const float* cw0   = (const float*)d_in[4];
    const float* io    = (const float*)d_in[5];
    const float* M0    = (const float*)d_in[6];
    const float* Wih_r = (const float*)d_in[7];
    const float* bih_r = (const float*)d_in[9];
    const float* bhh_r = (const float*)d_in[10];

    float* out = (float*)d_out;
    float* outputs = out;                    // [64][16][512]
    float* hrS1 = out + 524288;              // hr slot = hr parity-1 buf
    float* crS  = out + 532480;
    float* hwS1 = out + 540672;              // hw slot = hw parity-1 buf
    float* cwS  = out + 548864;
    float* Mw   = out + 557056;              // Mf (written once at epilogue)

    float* ws = (float*)d_ws;
    float* pre     = ws;                     // 1024*2048
    float* mbuf    = ws + 2097152;           // 32*512
    float* comppre = mbuf + 16384;           // 16*512
    float* hrB0    = comppre + 8192;         // hr parity 0
    float* hwB0    = hrB0 + 8192;            // hw parity 0
    float* mpart   = hwB0 + 8192;            // 256*512
    float* mxpart  = mpart + 131072;         // 256
    float* sumpart = mxpart + 256;           // 256
    unsigned* slots = (unsigned*)(sumpart + 256); // 256 uints

    (void)hipMemsetAsync(slots, 0, 256 * sizeof(unsigned), stream);

    k_pre<<<dim3(32, 16), 256, 0, stream>>>(emb, io, Wih_r, bih_r, bhh_r, pre);

    P p;
    p.pre = pre;
    p.Whh_r = (const float*)d_in[8];
    p.Wc    = (const float*)d_in[11];
    p.bc    = (const float*)d_in[12];
    p.Wih_w = (const float*)d_in[13];
    p.Whh_w = (const float*)d_in[14];
    p.bih_w = (const float*)d_in[15];
    p.bhh_w = (const float*)d_in[16];
    p.hr0 = hr0; p.cr0 = cr0; p.hw0 = hw0; p.cw0 = cw0; p.M0 = M0;
    p.mbuf = mbuf; p.comppre = comppre;
    p.mpart = mpart; p.mxpart = mxpart; p.sumpart = sumpart;
    p.hrb0 = hrB0; p.hrb1 = hrS1; p.crS = crS;
    p.hwb0 = hwB0; p.hwb1 = hwS1; p.cwS = cwS;
    p.outputs = outputs; p.Mw = Mw;
    p.slots = slots;

    k_persist<<<NBLK, 256, 0, stream>>>(p);
}